// Round 2
// baseline (252.880 us; speedup 1.0000x reference)
//
#include <hip/hip_runtime.h>
#include <hip/hip_fp16.h>

// Problem constants (from reference setup_inputs):
//   x: (1, 3, 128, 128) fp32
//   w: (3, 124, 124, 25, 5, 5) fp32   (last two dims = (u, v), v contiguous)
//   q: (3, 124, 124, 25, 5, 5) fp32
//   out: (1, 3, 124, 124, 25) fp32
// out[c,i,j,n] = sum_u log( prod_v (1.1 + atan(10*(x[c,i+u,j+v]*w[c,i,j,n,u,v]
//                                                 - q[c,i,j,n,u,v]))/pi) )
//
// R2 design: w/q staged through LDS as fp16 (halves LDS footprint:
// 51,200 -> 25,600 B/block -> 6 blocks/CU = 24 waves = 75% occupancy vs 30%).
// R1 was latency-bound: VALUBusy 16%, hbm 16%, occupancy 30% (LDS-capped).

#define IMG   128
#define OUT   124
#define NUM   25
#define SIDE  5
#define NOUT  (3 * OUT * OUT * NUM)            // 1,153,200 outputs
#define WTOT  ((long long)NOUT * NUM)          // 28,830,000 floats in w (and q)
#define OPB   256                              // outputs per block (= block size)
#define FPB   (OPB * NUM)                      // 6400 floats of w (and q) per block
#define FPB4  (FPB / 4)                        // 1600 float4 per block

// Minimax atan, |err| ~ 2e-6 over all inputs. Range-reduce with v_rcp_f32.
__device__ __forceinline__ float fast_atan(float z) {
    float az  = __builtin_fabsf(z);
    float r   = __builtin_amdgcn_rcpf(az);      // ~1 ulp approx reciprocal
    bool  big = az > 1.0f;
    float t   = big ? r : az;                   // t in [0, 1]
    float s   = t * t;
    float p   =                     -0.01172120f;
    p = __builtin_fmaf(p, s,         0.05265332f);
    p = __builtin_fmaf(p, s,        -0.11643287f);
    p = __builtin_fmaf(p, s,         0.19354346f);
    p = __builtin_fmaf(p, s,        -0.33262347f);
    p = __builtin_fmaf(p, s,         0.99997726f);
    float a = t * p;
    a = big ? (1.57079632679489662f - a) : a;
    return __builtin_copysignf(a, z);
}

// __launch_bounds__(256, 8): force VGPR <= 64 so occupancy isn't VGPR-capped
// (waves/CU halves at vgpr=64; R1 build was 68 VGPR).
__global__ __launch_bounds__(OPB, 8) void dendrite_kernel(
    const float* __restrict__ x,
    const float* __restrict__ w,
    const float* __restrict__ q,
    float* __restrict__ out)
{
    __shared__ __half lw[FPB];   // 12,800 B
    __shared__ __half lq[FPB];   // 12,800 B   -> 25,600 B total

    const int t   = threadIdx.x;
    const int blk = blockIdx.x;
    const long long base = (long long)blk * FPB;   // float index into w/q

    // ---- Cooperative, fully-coalesced float4 staging; fp32 -> fp16 in LDS ----
    // base*4 bytes = blk*25600 B -> 16B aligned. WTOT % 4 == 0, so the tail is
    // an exact number of float4s.
    const float4* w4 = (const float4*)(w + base);
    const float4* q4 = (const float4*)(q + base);
    float2* lw2 = (float2*)lw;   // one float2 = 4 packed halfs, 8B-aligned store
    float2* lq2 = (float2*)lq;
    const int nf4 = (int)(((WTOT - base) < (long long)FPB ? (WTOT - base) : (long long)FPB) >> 2);
    #pragma unroll
    for (int idx = t; idx < FPB4; idx += OPB) {
        if (idx < nf4) {
            float4 a = w4[idx];
            float4 b = q4[idx];
            union { __half2 h[2]; float2 f; } uw, uq;
            uw.h[0] = __floats2half2_rn(a.x, a.y);
            uw.h[1] = __floats2half2_rn(a.z, a.w);
            uq.h[0] = __floats2half2_rn(b.x, b.y);
            uq.h[1] = __floats2half2_rn(b.z, b.w);
            lw2[idx] = uw.f;
            lq2[idx] = uq.f;
        }
    }
    __syncthreads();

    // ---- One output per thread ----
    const int o = blk * OPB + t;
    if (o < NOUT) {
        int rem = o / NUM;                 // (c*OUT + i)*OUT + j
        const int j = rem % OUT;  rem /= OUT;
        const int i = rem % OUT;
        const int c = rem / OUT;

        const float* xp = x + ((long long)c * IMG + i) * IMG + j;  // patch base
        const __half* wp = lw + t * NUM;   // 50B lane stride: ~2 lanes/bank, free
        const __half* qp = lq + t * NUM;

        float acc = 0.0f;
        #pragma unroll
        for (int u = 0; u < SIDE; ++u) {
            float prod = 1.0f;
            #pragma unroll
            for (int v = 0; v < SIDE; ++v) {
                const float pv = xp[u * IMG + v];            // broadcast-heavy load
                const int   k  = u * SIDE + v;
                const float wv = __half2float(wp[k]);
                const float qv = __half2float(qp[k]);
                const float z  = 10.0f * __builtin_fmaf(pv, wv, -qv);
                const float a  = fast_atan(z);
                // (pi + 2a)/(2pi) + 0.6 = 1.1 + a/pi
                prod *= __builtin_fmaf(a, 0.31830988618379067f, 1.1f);
            }
            acc += __logf(prod);           // prod in (0.6^5, 1.6^5): safe
        }
        out[o] = acc;
    }
}

extern "C" void kernel_launch(void* const* d_in, const int* in_sizes, int n_in,
                              void* d_out, int out_size, void* d_ws, size_t ws_size,
                              hipStream_t stream) {
    const float* x = (const float*)d_in[0];
    const float* w = (const float*)d_in[1];
    const float* q = (const float*)d_in[2];
    float* out = (float*)d_out;

    const int grid = (NOUT + OPB - 1) / OPB;   // 4505 blocks
    dendrite_kernel<<<grid, OPB, 0, stream>>>(x, w, q, out);
}

// Round 3
// 246.475 us; speedup vs baseline: 1.0260x; 1.0260x over previous
//
#include <hip/hip_runtime.h>

// Problem constants (from reference setup_inputs):
//   x: (1, 3, 128, 128) fp32
//   w: (3, 124, 124, 25, 5, 5) fp32
//   q: (3, 124, 124, 25, 5, 5) fp32
//   out: (1, 3, 124, 124, 25) fp32
// out[o] = sum_u log( prod_v (1.1 + atan(10*(x*w - q))/pi) )
//        = log( prod_{k=0..24} (1.1 + atan(10*(x_k*w_k - q_k))/pi) )   [exact identity]
//
// R3 design: no LDS, no barrier, no phases. R1/R2 post-mortem: staging loop
// had only 2 loads outstanding (load->wait->store per iter) + vmcnt(0)+barrier
// drain -> MLP-starved at ~2.3 TB/s effective stream regardless of occupancy.
// Here each thread issues 14 independent w/q loads (13 KB/wave in flight, x7
// MLP) straight to registers; wave spans a contiguous 6400 B so L1 merges the
// per-instruction overlap and HBM traffic stays ideal.

#define IMG   128
#define OUT   124
#define NUM   25
#define NOUT  (3 * OUT * OUT * NUM)            // 1,153,200 outputs
#define OPB   256

// Minimax atan, |err| ~ 2e-6 over all inputs. Range-reduce with v_rcp_f32.
__device__ __forceinline__ float fast_atan(float z) {
    float az  = __builtin_fabsf(z);
    float r   = __builtin_amdgcn_rcpf(az);
    bool  big = az > 1.0f;
    float t   = big ? r : az;                   // t in [0, 1]
    float s   = t * t;
    float p   =                     -0.01172120f;
    p = __builtin_fmaf(p, s,         0.05265332f);
    p = __builtin_fmaf(p, s,        -0.11643287f);
    p = __builtin_fmaf(p, s,         0.19354346f);
    p = __builtin_fmaf(p, s,        -0.33262347f);
    p = __builtin_fmaf(p, s,         0.99997726f);
    float a = t * p;
    a = big ? (1.57079632679489662f - a) : a;
    return __builtin_copysignf(a, z);
}

// Dword-aligned (not 16B-aligned) 16-byte load. gfx950 global loads only
// need dword alignment; memcpy lets clang emit the widest legal load.
__device__ __forceinline__ float4 load4u(const float* p) {
    float4 v;
    __builtin_memcpy(&v, p, sizeof(float4));
    return v;
}

__global__ __launch_bounds__(OPB) void dendrite_kernel(
    const float* __restrict__ x,
    const float* __restrict__ w,
    const float* __restrict__ q,
    float* __restrict__ out)
{
    const int o = blockIdx.x * OPB + threadIdx.x;
    if (o >= NOUT) return;

    int rem = o / NUM;                 // (c*OUT + i)*OUT + j
    const int j = rem % OUT;  rem /= OUT;
    const int i = rem % OUT;
    const int c = rem / OUT;

    const float* wp = w + (long long)o * NUM;      // 100 B per lane, contiguous per wave
    const float* qp = q + (long long)o * NUM;
    const float* xp = x + ((long long)c * IMG + i) * IMG + j;

    // ---- Issue all loads up front: 14 independent w/q loads + 10 x loads ----
    float wv[NUM], qv[NUM], xv[NUM];
    #pragma unroll
    for (int g = 0; g < 6; ++g) {
        float4 a = load4u(wp + 4 * g);
        wv[4*g+0] = a.x; wv[4*g+1] = a.y; wv[4*g+2] = a.z; wv[4*g+3] = a.w;
    }
    wv[24] = wp[24];
    #pragma unroll
    for (int g = 0; g < 6; ++g) {
        float4 a = load4u(qp + 4 * g);
        qv[4*g+0] = a.x; qv[4*g+1] = a.y; qv[4*g+2] = a.z; qv[4*g+3] = a.w;
    }
    qv[24] = qp[24];
    #pragma unroll
    for (int u = 0; u < 5; ++u) {
        float4 a = load4u(xp + u * IMG);           // rows are L1-resident broadcasts
        xv[5*u+0] = a.x; xv[5*u+1] = a.y; xv[5*u+2] = a.z; xv[5*u+3] = a.w;
        xv[5*u+4] = xp[u * IMG + 4];
    }

    // ---- Pure VALU: 25 independent terms, 2 product chains for ILP ----
    float prod0 = 1.0f, prod1 = 1.0f;
    #pragma unroll
    for (int k = 0; k < NUM; ++k) {
        const float z = 10.0f * __builtin_fmaf(xv[k], wv[k], -qv[k]);
        const float a = fast_atan(z);
        const float term = __builtin_fmaf(a, 0.31830988618379067f, 1.1f);
        if (k & 1) prod1 *= term; else prod0 *= term;
    }
    // prod in (~0.6^25, ~1.6^25) = (2.8e-6, 1.3e5): fp32-safe, single log.
    out[o] = __logf(prod0 * prod1);
}

extern "C" void kernel_launch(void* const* d_in, const int* in_sizes, int n_in,
                              void* d_out, int out_size, void* d_ws, size_t ws_size,
                              hipStream_t stream) {
    const float* x = (const float*)d_in[0];
    const float* w = (const float*)d_in[1];
    const float* q = (const float*)d_in[2];
    float* out = (float*)d_out;

    const int grid = (NOUT + OPB - 1) / OPB;   // 4505 blocks
    dendrite_kernel<<<grid, OPB, 0, stream>>>(x, w, q, out);
}